// Round 1
// baseline (213.484 us; speedup 1.0000x reference)
//
#include <hip/hip_runtime.h>
#include <math.h>

#define DEV __device__ __forceinline__

struct C2 { float x, y; };
DEV C2 cmul(C2 a, C2 b){ return {a.x*b.x - a.y*b.y, a.x*b.y + a.y*b.x}; }
DEV C2 cadd(C2 a, C2 b){ return {a.x+b.x, a.y+b.y}; }
DEV C2 cscale(C2 a, float s){ return {a.x*s, a.y*s}; }
DEV C2 cnegi(C2 a){ return {a.y, -a.x}; } // multiply by -i

// ---------------------------------------------------------------------------
// K1: k_states = key @ Wk + bk  (per row: 512 -> 16), then analytic quantum
// score per row. One wave per row; lanes split as 4 groups x 16 output cols.
// ---------------------------------------------------------------------------
__global__ __launch_bounds__(256) void k_scores(const float* __restrict__ key,
                                                const float* __restrict__ Wk,
                                                const float* __restrict__ bk,
                                                float* __restrict__ score,
                                                int nrows)
{
    int wave = (int)((blockIdx.x * blockDim.x + threadIdx.x) >> 6);
    int lane = threadIdx.x & 63;
    if (wave >= nrows) return;
    int group = lane >> 4;        // 0..3 -> e-range [group*128, group*128+128)
    int k     = lane & 15;        // output column 0..15

    const float4* krow4 = (const float4*)(key + (size_t)wave * 512) + group * 32;
    float acc = 0.f;
    #pragma unroll 4
    for (int i = 0; i < 32; ++i) {
        float4 kv = krow4[i];
        int e = group * 128 + i * 4;
        acc = fmaf(kv.x, Wk[(e + 0) * 16 + k], acc);
        acc = fmaf(kv.y, Wk[(e + 1) * 16 + k], acc);
        acc = fmaf(kv.z, Wk[(e + 2) * 16 + k], acc);
        acc = fmaf(kv.w, Wk[(e + 3) * 16 + k], acc);
    }
    // reduce the 4 e-groups (lanes l, l^16, l^32, l^48)
    acc += __shfl_xor(acc, 16);
    acc += __shfl_xor(acc, 32);
    float ks = acc + bk[k];       // lane l holds k_states[l & 15]

    // gather the 16 angles into every lane
    float th[16];
    #pragma unroll
    for (int t = 0; t < 16; ++t) th[t] = __shfl(ks, t);

    if (lane == 0) {
        // entangled base per pair: (1/sqrt2)[|00> + c0|10> - i s0|11>],
        // theta = pi*0.8, c0 = cos(theta/2), s0 = sin(theta/2)
        const float c0 = 0.30901699437494745f;
        const float s0 = 0.9510565162951535f;
        float total = 0.f;
        #pragma unroll
        for (int p = 0; p < 4; ++p) {
            float ax = th[4*p+0], az = th[4*p+1];  // qubit 2p   (x, z)
            float bx = th[4*p+2], bz = th[4*p+3];  // qubit 2p+1 (x, z)
            float cxa = 1.f, sxa = 0.f; if (ax > 0.f) sincosf(0.5f*ax, &sxa, &cxa);
            float cpa = 1.f, spa = 0.f; if (az > 0.f) sincosf(0.5f*az, &spa, &cpa);
            float cxb = 1.f, sxb = 0.f; if (bx > 0.f) sincosf(0.5f*bx, &sxb, &cxb);
            float cpb = 1.f, spb = 0.f; if (bz > 0.f) sincosf(0.5f*bz, &spb, &cpb);
            // G = Rz(z)·Rx(x): [[e^-ip cx, -i e^-ip sx],[-i e^ip sx, e^ip cx]]
            C2 A00{cpa*cxa, -spa*cxa}, A01{-spa*sxa, -cpa*sxa};
            C2 A10{spa*sxa, -cpa*sxa}, A11{ cpa*cxa,  spa*cxa};
            C2 B00{cpb*cxb, -spb*cxb}, B01{-spb*sxb, -cpb*sxb};
            C2 B10{spb*sxb, -cpb*sxb}, B11{ cpb*cxb,  spb*cxb};
            C2 u = cadd(cmul(B00, cadd(A00, cscale(A01, c0))),
                        cscale(cnegi(cmul(A01, B01)), s0));
            C2 v = cadd(cmul(B10, cadd(A10, cscale(A11, c0))),
                        cscale(cnegi(cmul(A11, B11)), s0));
            total += 0.5f * (u.x*u.x + u.y*u.y + v.x*v.x + v.y*v.y);
        }
        score[wave] = total * 0.25f;
    }
}

// ---------------------------------------------------------------------------
// K2: softmax over S=2048 per batch. 8 blocks x 256 threads, 8 elems/thread.
// ---------------------------------------------------------------------------
__global__ __launch_bounds__(256) void k_softmax(const float* __restrict__ score,
                                                 float* __restrict__ p)
{
    int b = blockIdx.x, t = threadIdx.x;
    const float* s = score + b * 2048;
    float vals[8]; float m = -1e30f;
    #pragma unroll
    for (int i = 0; i < 8; ++i) { vals[i] = s[t + 256*i]; m = fmaxf(m, vals[i]); }
    __shared__ float red[256];
    red[t] = m; __syncthreads();
    for (int off = 128; off > 0; off >>= 1) {
        if (t < off) red[t] = fmaxf(red[t], red[t + off]);
        __syncthreads();
    }
    m = red[0]; __syncthreads();
    float e[8]; float sum = 0.f;
    #pragma unroll
    for (int i = 0; i < 8; ++i) { e[i] = expf(vals[i] - m); sum += e[i]; }
    red[t] = sum; __syncthreads();
    for (int off = 128; off > 0; off >>= 1) {
        if (t < off) red[t] += red[t + off];
        __syncthreads();
    }
    float inv = 1.f / red[0];
    float* pb = p + b * 2048;
    #pragma unroll
    for (int i = 0; i < 8; ++i) pb[t + 256*i] = e[i] * inv;
}

// ---------------------------------------------------------------------------
// K3: partial weighted sums of value rows: partial[b,c,:] = sum_{j in chunk c}
// p[b,j] * value[b,j,:].  grid (64 chunks, 8 batches), 128 thr (float4 cols).
// ---------------------------------------------------------------------------
__global__ __launch_bounds__(128) void k_wsum_partial(const float* __restrict__ value,
                                                      const float* __restrict__ p,
                                                      float* __restrict__ partial)
{
    int c = blockIdx.x;   // 0..63, 32 rows each
    int b = blockIdx.y;   // 0..7
    int t = threadIdx.x;  // 0..127 -> float4 column
    const float4* vbase = (const float4*)value + ((size_t)b*2048 + c*32) * 128 + t;
    const float*  pb    = p + b*2048 + c*32;
    float4 acc = {0.f, 0.f, 0.f, 0.f};
    #pragma unroll 8
    for (int j = 0; j < 32; ++j) {
        float w = pb[j];                      // wave-uniform -> scalar load
        float4 v = vbase[(size_t)j * 128];
        acc.x = fmaf(w, v.x, acc.x); acc.y = fmaf(w, v.y, acc.y);
        acc.z = fmaf(w, v.z, acc.z); acc.w = fmaf(w, v.w, acc.w);
    }
    ((float4*)partial)[((size_t)b*64 + c) * 128 + t] = acc;
}

// K4: vbar[b,e] = sum_c partial[b,c,e]
__global__ __launch_bounds__(256) void k_vbar(const float* __restrict__ partial,
                                              float* __restrict__ vbar)
{
    int idx = blockIdx.x * 256 + threadIdx.x;  // 0..4095
    int b = idx >> 9, e = idx & 511;
    float s = 0.f;
    for (int c = 0; c < 64; ++c) s += partial[((size_t)b*64 + c) * 512 + e];
    vbar[idx] = s;
}

// ---------------------------------------------------------------------------
// K5/K6: xout[b,:] = xin[b,:] @ W + bias  for 8 rows of 512.
// grid (8 d-tiles, 8 batches); 256 thr = 64 d-cols x 4 e-quarters.
// ---------------------------------------------------------------------------
__global__ __launch_bounds__(256) void k_gemm8(const float* __restrict__ xin,
                                               const float* __restrict__ W,
                                               const float* __restrict__ bias,
                                               float* __restrict__ xout)
{
    int dt = blockIdx.x, b = blockIdx.y, t = threadIdx.x;
    int dl = t & 63, q = t >> 6;
    int d = dt * 64 + dl;
    const float* x  = xin + b * 512 + q * 128;
    const float* Wc = W + (size_t)(q * 128) * 512 + d;
    float acc = 0.f;
    #pragma unroll 4
    for (int e = 0; e < 128; ++e) acc = fmaf(x[e], Wc[(size_t)e * 512], acc);
    __shared__ float red[256];
    red[t] = acc; __syncthreads();
    if (t < 64) {
        float tot = red[t] + red[t+64] + red[t+128] + red[t+192] + bias[d];
        xout[b * 512 + d] = tot;
    }
}

// K7: out[b,i,:] = frow[b,:] for all i (pure broadcast write, float4).
__global__ __launch_bounds__(256) void k_broadcast(const float* __restrict__ frow,
                                                   float* __restrict__ out)
{
    const size_t total4 = (size_t)8 * 2048 * 128;  // 2097152 float4
    size_t idx = (size_t)blockIdx.x * blockDim.x + threadIdx.x;
    size_t stride = (size_t)gridDim.x * blockDim.x;
    const float4* f4 = (const float4*)frow;
    float4* o4 = (float4*)out;
    for (size_t i = idx; i < total4; i += stride) {
        size_t b   = i >> 18;   // / (2048*128)
        size_t col = i & 127;   // float4 col within row
        o4[i] = f4[b * 128 + col];
    }
}

extern "C" void kernel_launch(void* const* d_in, const int* in_sizes, int n_in,
                              void* d_out, int out_size, void* d_ws, size_t ws_size,
                              hipStream_t stream) {
    // setup_inputs order: query, key, value, Wq, bq, Wk, bk, Wv, bv, Wo, bo
    const float* key   = (const float*)d_in[1];
    const float* value = (const float*)d_in[2];
    const float* Wk    = (const float*)d_in[5];
    const float* bk    = (const float*)d_in[6];
    const float* Wv    = (const float*)d_in[7];
    const float* bv    = (const float*)d_in[8];
    const float* Wo    = (const float*)d_in[9];
    const float* bo    = (const float*)d_in[10];
    float* out = (float*)d_out;
    float* ws  = (float*)d_ws;

    // workspace layout (floats)
    float* score   = ws;                 // 16384
    float* p       = ws + 16384;         // 16384
    float* partial = ws + 32768;         // 8*64*512 = 262144
    float* vbar    = ws + 294912;        // 4096
    float* ctx     = ws + 299008;        // 4096
    float* frow    = ws + 303104;        // 4096   (total ~1.2 MB)

    k_scores      <<<4096, 256, 0, stream>>>(key, Wk, bk, score, 16384);
    k_softmax     <<<8, 256, 0, stream>>>(score, p);
    k_wsum_partial<<<dim3(64, 8), 128, 0, stream>>>(value, p, partial);
    k_vbar        <<<16, 256, 0, stream>>>(partial, vbar);
    k_gemm8       <<<dim3(8, 8), 256, 0, stream>>>(vbar, Wv, bv, ctx);
    k_gemm8       <<<dim3(8, 8), 256, 0, stream>>>(ctx, Wo, bo, frow);
    k_broadcast   <<<2048, 256, 0, stream>>>(frow, out);
}

// Round 2
// 193.622 us; speedup vs baseline: 1.1026x; 1.1026x over previous
//
#include <hip/hip_runtime.h>
#include <math.h>

#define DEV __device__ __forceinline__

struct C2 { float x, y; };
DEV C2 cmul(C2 a, C2 b){ return {a.x*b.x - a.y*b.y, a.x*b.y + a.y*b.x}; }
DEV C2 cadd(C2 a, C2 b){ return {a.x+b.x, a.y+b.y}; }
DEV C2 cscale(C2 a, float s){ return {a.x*s, a.y*s}; }
DEV C2 cnegi(C2 a){ return {a.y, -a.x}; } // multiply by -i

// ---------------------------------------------------------------------------
// K1: k_states = key @ Wk + bk (512->16) + analytic quantum score, one row
// per wave per grid-stride iter. Lane l owns e in {4l..4l+3, 256+4l..+3}
// (coalesced float4 x2); Wk slice (8 rows x 16) lives in registers, loaded
// once per wave. Multi-value butterfly: 16 accs -> 1 in 4 stages; lane l
// ends with k_states[l&15]. Score: lane computes pair (l&3), 2-shfl reduce.
// ---------------------------------------------------------------------------
__global__ __launch_bounds__(256) void k_scores(const float* __restrict__ key,
                                                const float* __restrict__ Wk,
                                                const float* __restrict__ bk,
                                                float* __restrict__ score)
{
    const int lane = threadIdx.x & 63;
    const int wid  = blockIdx.x * (blockDim.x >> 6) + (threadIdx.x >> 6);
    const int nw   = gridDim.x * (blockDim.x >> 6);

    // per-lane Wk slice: rows 4l..4l+3 and 256+4l..256+4l+3, all 16 cols
    float4 wk[8][4];
    #pragma unroll
    for (int jj = 0; jj < 4; ++jj) {
        const float4* w0 = (const float4*)(Wk + (4 * lane + jj) * 16);
        const float4* w1 = (const float4*)(Wk + (256 + 4 * lane + jj) * 16);
        #pragma unroll
        for (int q = 0; q < 4; ++q) { wk[jj][q] = w0[q]; wk[4 + jj][q] = w1[q]; }
    }
    const float bkr = bk[lane & 15];
    const float c0 = 0.30901699437494745f;   // cos(pi*0.8/2)
    const float s0 = 0.9510565162951535f;    // sin(pi*0.8/2)

    for (int r = wid; r < 16384; r += nw) {
        const float4* kp = (const float4*)(key + (size_t)r * 512);
        float4 k0 = kp[lane];       // e = 4l..4l+3
        float4 k1 = kp[64 + lane];  // e = 256+4l..+3
        float el[8] = {k0.x, k0.y, k0.z, k0.w, k1.x, k1.y, k1.z, k1.w};
        float acc[16];
        #pragma unroll
        for (int k = 0; k < 16; ++k) acc[k] = 0.f;
        #pragma unroll
        for (int j = 0; j < 8; ++j) {
            #pragma unroll
            for (int q = 0; q < 4; ++q) {
                acc[4*q+0] = fmaf(el[j], wk[j][q].x, acc[4*q+0]);
                acc[4*q+1] = fmaf(el[j], wk[j][q].y, acc[4*q+1]);
                acc[4*q+2] = fmaf(el[j], wk[j][q].z, acc[4*q+2]);
                acc[4*q+3] = fmaf(el[j], wk[j][q].w, acc[4*q+3]);
            }
        }
        // butterfly: stage s halves reg count; after 4 stages acc[0] holds
        // output (lane&15) summed over this 16-lane group's e's.
        #pragma unroll
        for (int s = 0; s < 4; ++s) {
            const int m = 1 << s;
            const int bbit = (lane >> s) & 1;
            #pragma unroll
            for (int j = 0; j < (16 >> (s + 1)); ++j) {
                float send = bbit ? acc[2*j] : acc[2*j+1];
                float keep = bbit ? acc[2*j+1] : acc[2*j];
                float got  = __shfl_xor(send, m);
                acc[j] = keep + got;
            }
        }
        float ks = acc[0];
        ks += __shfl_xor(ks, 16);
        ks += __shfl_xor(ks, 32);
        ks += bkr;                  // lane l holds k_states[row][l & 15]

        // quantum score: lane handles pair pp = l&3
        int pp = lane & 3;
        float ax = __shfl(ks, 4*pp+0);
        float az = __shfl(ks, 4*pp+1);
        float bx = __shfl(ks, 4*pp+2);
        float bz = __shfl(ks, 4*pp+3);
        float cxa = 1.f, sxa = 0.f; if (ax > 0.f){ sxa = __sinf(0.5f*ax); cxa = __cosf(0.5f*ax); }
        float cpa = 1.f, spa = 0.f; if (az > 0.f){ spa = __sinf(0.5f*az); cpa = __cosf(0.5f*az); }
        float cxb = 1.f, sxb = 0.f; if (bx > 0.f){ sxb = __sinf(0.5f*bx); cxb = __cosf(0.5f*bx); }
        float cpb = 1.f, spb = 0.f; if (bz > 0.f){ spb = __sinf(0.5f*bz); cpb = __cosf(0.5f*bz); }
        C2 A00{cpa*cxa, -spa*cxa}, A01{-spa*sxa, -cpa*sxa};
        C2 A10{spa*sxa, -cpa*sxa}, A11{ cpa*cxa,  spa*cxa};
        C2 B00{cpb*cxb, -spb*cxb}, B01{-spb*sxb, -cpb*sxb};
        C2 B10{spb*sxb, -cpb*sxb}, B11{ cpb*cxb,  spb*cxb};
        C2 u = cadd(cmul(B00, cadd(A00, cscale(A01, c0))),
                    cscale(cnegi(cmul(A01, B01)), s0));
        C2 v = cadd(cmul(B10, cadd(A10, cscale(A11, c0))),
                    cscale(cnegi(cmul(A11, B11)), s0));
        float ps = u.x*u.x + u.y*u.y + v.x*v.x + v.y*v.y;
        ps += __shfl_xor(ps, 1);
        ps += __shfl_xor(ps, 2);    // sum of 4 pairs
        if (lane == 0) score[r] = ps * 0.125f;  // *0.5 (base norm) *0.25 (mean)
    }
}

// ---------------------------------------------------------------------------
// K2: softmax over S=2048 per batch (proven round-1 version).
// ---------------------------------------------------------------------------
__global__ __launch_bounds__(256) void k_softmax(const float* __restrict__ score,
                                                 float* __restrict__ p)
{
    int b = blockIdx.x, t = threadIdx.x;
    const float* s = score + b * 2048;
    float vals[8]; float m = -1e30f;
    #pragma unroll
    for (int i = 0; i < 8; ++i) { vals[i] = s[t + 256*i]; m = fmaxf(m, vals[i]); }
    __shared__ float red[256];
    red[t] = m; __syncthreads();
    for (int off = 128; off > 0; off >>= 1) {
        if (t < off) red[t] = fmaxf(red[t], red[t + off]);
        __syncthreads();
    }
    m = red[0]; __syncthreads();
    float e[8]; float sum = 0.f;
    #pragma unroll
    for (int i = 0; i < 8; ++i) { e[i] = expf(vals[i] - m); sum += e[i]; }
    red[t] = sum; __syncthreads();
    for (int off = 128; off > 0; off >>= 1) {
        if (t < off) red[t] += red[t + off];
        __syncthreads();
    }
    float inv = 1.f / red[0];
    float* pb = p + b * 2048;
    #pragma unroll
    for (int i = 0; i < 8; ++i) pb[t + 256*i] = e[i] * inv;
}

// ---------------------------------------------------------------------------
// K3: weighted partial sums of value rows. grid (64 chunks, 8 b), 256 thr:
// col4 = t&127, row-group = t>>7 (16 rows each), LDS-combine the two groups.
// ---------------------------------------------------------------------------
__global__ __launch_bounds__(256) void k_wsum_partial(const float* __restrict__ value,
                                                      const float* __restrict__ p,
                                                      float* __restrict__ partial)
{
    int c = blockIdx.x;   // 0..63 -> rows c*32..c*32+31
    int b = blockIdx.y;   // 0..7
    int t = threadIdx.x;
    int col4 = t & 127, rg = t >> 7;
    const float4* vbase = (const float4*)value
        + ((size_t)b*2048 + c*32 + rg*16) * 128 + col4;
    const float* pb = p + b*2048 + c*32 + rg*16;
    float4 acc = {0.f, 0.f, 0.f, 0.f};
    #pragma unroll 4
    for (int j = 0; j < 16; ++j) {
        float w = pb[j];                      // wave-uniform -> scalar load
        float4 v = vbase[(size_t)j * 128];
        acc.x = fmaf(w, v.x, acc.x); acc.y = fmaf(w, v.y, acc.y);
        acc.z = fmaf(w, v.z, acc.z); acc.w = fmaf(w, v.w, acc.w);
    }
    __shared__ float4 tmp[128];
    if (rg) tmp[col4] = acc;
    __syncthreads();
    if (!rg) {
        float4 o = tmp[col4];
        acc.x += o.x; acc.y += o.y; acc.z += o.z; acc.w += o.w;
        ((float4*)partial)[((size_t)b*64 + c) * 128 + col4] = acc;
    }
}

// K4: vbar[b,e] = sum_c partial[b,c,e]
__global__ __launch_bounds__(256) void k_vbar(const float* __restrict__ partial,
                                              float* __restrict__ vbar)
{
    int idx = blockIdx.x * 256 + threadIdx.x;  // 0..4095
    int b = idx >> 9, e = idx & 511;
    float s = 0.f;
    #pragma unroll 4
    for (int c = 0; c < 64; ++c) s += partial[((size_t)b*64 + c) * 512 + e];
    vbar[idx] = s;
}

// ---------------------------------------------------------------------------
// K5/K6: xout[b,:] = xin[b,:] @ W + bias for 8 rows of 512.
// ---------------------------------------------------------------------------
__global__ __launch_bounds__(256) void k_gemm8(const float* __restrict__ xin,
                                               const float* __restrict__ W,
                                               const float* __restrict__ bias,
                                               float* __restrict__ xout)
{
    int dt = blockIdx.x, b = blockIdx.y, t = threadIdx.x;
    int dl = t & 63, q = t >> 6;
    int d = dt * 64 + dl;
    const float* x  = xin + b * 512 + q * 128;
    const float* Wc = W + (size_t)(q * 128) * 512 + d;
    float acc = 0.f;
    #pragma unroll 4
    for (int e = 0; e < 128; ++e) acc = fmaf(x[e], Wc[(size_t)e * 512], acc);
    __shared__ float red[256];
    red[t] = acc; __syncthreads();
    if (t < 64) {
        float tot = red[t] + red[t+64] + red[t+128] + red[t+192] + bias[d];
        xout[b * 512 + d] = tot;
    }
}

// K7: out[b,i,:] = frow[b,:] for all i (pure broadcast write, float4).
__global__ __launch_bounds__(256) void k_broadcast(const float* __restrict__ frow,
                                                   float* __restrict__ out)
{
    const size_t total4 = (size_t)8 * 2048 * 128;  // 2097152 float4
    size_t idx = (size_t)blockIdx.x * blockDim.x + threadIdx.x;
    size_t stride = (size_t)gridDim.x * blockDim.x;
    const float4* f4 = (const float4*)frow;
    float4* o4 = (float4*)out;
    for (size_t i = idx; i < total4; i += stride) {
        size_t b   = i >> 18;   // / (2048*128)
        size_t col = i & 127;   // float4 col within row
        o4[i] = f4[b * 128 + col];
    }
}

extern "C" void kernel_launch(void* const* d_in, const int* in_sizes, int n_in,
                              void* d_out, int out_size, void* d_ws, size_t ws_size,
                              hipStream_t stream) {
    // setup_inputs order: query, key, value, Wq, bq, Wk, bk, Wv, bv, Wo, bo
    const float* key   = (const float*)d_in[1];
    const float* value = (const float*)d_in[2];
    const float* Wk    = (const float*)d_in[5];
    const float* bk    = (const float*)d_in[6];
    const float* Wv    = (const float*)d_in[7];
    const float* bv    = (const float*)d_in[8];
    const float* Wo    = (const float*)d_in[9];
    const float* bo    = (const float*)d_in[10];
    float* out = (float*)d_out;
    float* ws  = (float*)d_ws;

    // workspace layout (floats), total ~1.2 MB
    float* score   = ws;                 // 16384
    float* p       = ws + 16384;         // 16384
    float* partial = ws + 32768;         // 8*64*512 = 262144
    float* vbar    = ws + 294912;        // 4096
    float* ctx     = ws + 299008;        // 4096
    float* frow    = ws + 303104;        // 4096

    k_scores      <<<512, 256, 0, stream>>>(key, Wk, bk, score);
    k_softmax     <<<8, 256, 0, stream>>>(score, p);
    k_wsum_partial<<<dim3(64, 8), 256, 0, stream>>>(value, p, partial);
    k_vbar        <<<16, 256, 0, stream>>>(partial, vbar);
    k_gemm8       <<<dim3(8, 8), 256, 0, stream>>>(vbar, Wv, bv, ctx);
    k_gemm8       <<<dim3(8, 8), 256, 0, stream>>>(ctx, Wo, bo, frow);
    k_broadcast   <<<2048, 256, 0, stream>>>(frow, out);
}

// Round 3
// 188.856 us; speedup vs baseline: 1.1304x; 1.0252x over previous
//
#include <hip/hip_runtime.h>
#include <math.h>

#define DEV __device__ __forceinline__

struct C2 { float x, y; };
DEV C2 cmul(C2 a, C2 b){ return {a.x*b.x - a.y*b.y, a.x*b.y + a.y*b.x}; }
DEV C2 cadd(C2 a, C2 b){ return {a.x+b.x, a.y+b.y}; }
DEV C2 cscale(C2 a, float s){ return {a.x*s, a.y*s}; }
DEV C2 cnegi(C2 a){ return {a.y, -a.x}; } // multiply by -i

// ---------------------------------------------------------------------------
// K1: k_states = key @ Wk + bk (512->16) + analytic quantum score; emits
// w[r] = exp(score[r]) (score in [0,1] -> no max subtraction needed).
// One row per wave per grid-stride iter; Wk slice in registers.
// ---------------------------------------------------------------------------
__global__ __launch_bounds__(256) void k_scores(const float* __restrict__ key,
                                                const float* __restrict__ Wk,
                                                const float* __restrict__ bk,
                                                float* __restrict__ w)
{
    const int lane = threadIdx.x & 63;
    const int wid  = blockIdx.x * (blockDim.x >> 6) + (threadIdx.x >> 6);
    const int nw   = gridDim.x * (blockDim.x >> 6);

    // per-lane Wk slice: rows 4l..4l+3 and 256+4l..256+4l+3, all 16 cols
    float4 wk[8][4];
    #pragma unroll
    for (int jj = 0; jj < 4; ++jj) {
        const float4* w0 = (const float4*)(Wk + (4 * lane + jj) * 16);
        const float4* w1 = (const float4*)(Wk + (256 + 4 * lane + jj) * 16);
        #pragma unroll
        for (int q = 0; q < 4; ++q) { wk[jj][q] = w0[q]; wk[4 + jj][q] = w1[q]; }
    }
    const float bkr = bk[lane & 15];
    const float c0 = 0.30901699437494745f;   // cos(pi*0.8/2)
    const float s0 = 0.9510565162951535f;    // sin(pi*0.8/2)

    for (int r = wid; r < 16384; r += nw) {
        const float4* kp = (const float4*)(key + (size_t)r * 512);
        float4 k0 = kp[lane];       // e = 4l..4l+3
        float4 k1 = kp[64 + lane];  // e = 256+4l..+3
        float el[8] = {k0.x, k0.y, k0.z, k0.w, k1.x, k1.y, k1.z, k1.w};
        float acc[16];
        #pragma unroll
        for (int k = 0; k < 16; ++k) acc[k] = 0.f;
        #pragma unroll
        for (int j = 0; j < 8; ++j) {
            #pragma unroll
            for (int q = 0; q < 4; ++q) {
                acc[4*q+0] = fmaf(el[j], wk[j][q].x, acc[4*q+0]);
                acc[4*q+1] = fmaf(el[j], wk[j][q].y, acc[4*q+1]);
                acc[4*q+2] = fmaf(el[j], wk[j][q].z, acc[4*q+2]);
                acc[4*q+3] = fmaf(el[j], wk[j][q].w, acc[4*q+3]);
            }
        }
        // butterfly: after 4 stages acc[0] holds output (lane&15) for this
        // 16-lane group's e's; then fold the 4 groups.
        #pragma unroll
        for (int s = 0; s < 4; ++s) {
            const int m = 1 << s;
            const int bbit = (lane >> s) & 1;
            #pragma unroll
            for (int j = 0; j < (16 >> (s + 1)); ++j) {
                float send = bbit ? acc[2*j] : acc[2*j+1];
                float keep = bbit ? acc[2*j+1] : acc[2*j];
                float got  = __shfl_xor(send, m);
                acc[j] = keep + got;
            }
        }
        float ks = acc[0];
        ks += __shfl_xor(ks, 16);
        ks += __shfl_xor(ks, 32);
        ks += bkr;                  // lane l holds k_states[row][l & 15]

        // quantum score: lane handles pair pp = l&3
        int pp = lane & 3;
        float ax = __shfl(ks, 4*pp+0);
        float az = __shfl(ks, 4*pp+1);
        float bx = __shfl(ks, 4*pp+2);
        float bz = __shfl(ks, 4*pp+3);
        float cxa = 1.f, sxa = 0.f; if (ax > 0.f){ sxa = __sinf(0.5f*ax); cxa = __cosf(0.5f*ax); }
        float cpa = 1.f, spa = 0.f; if (az > 0.f){ spa = __sinf(0.5f*az); cpa = __cosf(0.5f*az); }
        float cxb = 1.f, sxb = 0.f; if (bx > 0.f){ sxb = __sinf(0.5f*bx); cxb = __cosf(0.5f*bx); }
        float cpb = 1.f, spb = 0.f; if (bz > 0.f){ spb = __sinf(0.5f*bz); cpb = __cosf(0.5f*bz); }
        C2 A00{cpa*cxa, -spa*cxa}, A01{-spa*sxa, -cpa*sxa};
        C2 A10{spa*sxa, -cpa*sxa}, A11{ cpa*cxa,  spa*cxa};
        C2 B00{cpb*cxb, -spb*cxb}, B01{-spb*sxb, -cpb*sxb};
        C2 B10{spb*sxb, -cpb*sxb}, B11{ cpb*cxb,  spb*cxb};
        C2 u = cadd(cmul(B00, cadd(A00, cscale(A01, c0))),
                    cscale(cnegi(cmul(A01, B01)), s0));
        C2 v = cadd(cmul(B10, cadd(A10, cscale(A11, c0))),
                    cscale(cnegi(cmul(A11, B11)), s0));
        float ps = u.x*u.x + u.y*u.y + v.x*v.x + v.y*v.y;
        ps += __shfl_xor(ps, 1);
        ps += __shfl_xor(ps, 2);    // sum of 4 pairs
        if (lane == 0) w[r] = __expf(ps * 0.125f);
    }
}

// ---------------------------------------------------------------------------
// K2: unnormalized weighted partial sums of value rows + per-chunk w-sums.
// grid (64 chunks, 8 b), 256 thr: col4 = t&127, row-group = t>>7.
// ---------------------------------------------------------------------------
__global__ __launch_bounds__(256) void k_wsum(const float* __restrict__ value,
                                              const float* __restrict__ w,
                                              float* __restrict__ partial,
                                              float* __restrict__ partialw)
{
    int c = blockIdx.x;   // 0..63 -> rows c*32..c*32+31
    int b = blockIdx.y;   // 0..7
    int t = threadIdx.x;
    int col4 = t & 127, rg = t >> 7;
    const float4* vbase = (const float4*)value
        + ((size_t)b*2048 + c*32 + rg*16) * 128 + col4;
    const float* pb = w + b*2048 + c*32 + rg*16;
    float4 acc = {0.f, 0.f, 0.f, 0.f};
    #pragma unroll 4
    for (int j = 0; j < 16; ++j) {
        float wj = pb[j];                     // wave-uniform -> scalar load
        float4 v = vbase[(size_t)j * 128];
        acc.x = fmaf(wj, v.x, acc.x); acc.y = fmaf(wj, v.y, acc.y);
        acc.z = fmaf(wj, v.z, acc.z); acc.w = fmaf(wj, v.w, acc.w);
    }
    __shared__ float4 tmp[128];
    if (rg) tmp[col4] = acc;
    __syncthreads();
    if (!rg) {
        float4 o = tmp[col4];
        acc.x += o.x; acc.y += o.y; acc.z += o.z; acc.w += o.w;
        ((float4*)partial)[((size_t)b*64 + c) * 128 + col4] = acc;
    }
    // per-chunk weight sum (lanes 0..31 of wave 0)
    if (t < 32) {
        float wv = w[b*2048 + c*32 + t];
        wv += __shfl_xor(wv, 1);  wv += __shfl_xor(wv, 2);
        wv += __shfl_xor(wv, 4);  wv += __shfl_xor(wv, 8);
        wv += __shfl_xor(wv, 16);
        if (t == 0) partialw[b*64 + c] = wv;
    }
}

// ---------------------------------------------------------------------------
// K3: per block (dt, b): invS = 1/sum(partialw[b,:]); vbar = invS * reduce
// partial over chunks (into LDS); ctx[b, dt*64..+64] = vbar @ Wv + bv.
// ---------------------------------------------------------------------------
__global__ __launch_bounds__(256) void k_ctx(const float* __restrict__ partial,
                                             const float* __restrict__ partialw,
                                             const float* __restrict__ Wv,
                                             const float* __restrict__ bv,
                                             float* __restrict__ ctx)
{
    int dt = blockIdx.x, b = blockIdx.y, t = threadIdx.x;
    __shared__ float vb[512];
    __shared__ float invS;
    __shared__ float red[256];

    if (t < 64) {
        float s = partialw[b * 64 + t];
        s += __shfl_xor(s, 1);  s += __shfl_xor(s, 2);
        s += __shfl_xor(s, 4);  s += __shfl_xor(s, 8);
        s += __shfl_xor(s, 16); s += __shfl_xor(s, 32);
        if (t == 0) invS = 1.f / s;
    }
    float a0 = 0.f, a1 = 0.f;
    const float* pp = partial + (size_t)b * 64 * 512;
    #pragma unroll 4
    for (int c = 0; c < 64; ++c) {
        a0 += pp[c * 512 + t];
        a1 += pp[c * 512 + 256 + t];
    }
    __syncthreads();                 // invS visible
    vb[t] = a0 * invS; vb[t + 256] = a1 * invS;
    __syncthreads();                 // vb visible

    int dl = t & 63, q = t >> 6;
    int d = dt * 64 + dl;
    const float* x  = vb + q * 128;
    const float* Wc = Wv + (size_t)(q * 128) * 512 + d;
    float acc = 0.f;
    #pragma unroll 4
    for (int e = 0; e < 128; ++e) acc = fmaf(x[e], Wc[(size_t)e * 512], acc);
    red[t] = acc; __syncthreads();
    if (t < 64)
        ctx[b * 512 + dt * 64 + t] = red[t] + red[t+64] + red[t+128] + red[t+192]
                                   + bv[dt * 64 + t];
}

// ---------------------------------------------------------------------------
// K4: per block (dt, b, is): frow_tile = ctx[b,:] @ Wo[:, dt*64..+64] + bo,
// then broadcast-write to out[b, is*128..+128, dt*64..+64].
// ---------------------------------------------------------------------------
__global__ __launch_bounds__(256) void k_out(const float* __restrict__ ctx,
                                             const float* __restrict__ Wo,
                                             const float* __restrict__ bo,
                                             float* __restrict__ out)
{
    int dt = blockIdx.x, b = blockIdx.y, is = blockIdx.z, t = threadIdx.x;
    __shared__ float xs[512];
    __shared__ float red[256];
    __shared__ float4 frow4[16];

    xs[t]       = ctx[b * 512 + t];
    xs[t + 256] = ctx[b * 512 + 256 + t];
    __syncthreads();

    int dl = t & 63, q = t >> 6;
    int d = dt * 64 + dl;
    const float* x  = xs + q * 128;
    const float* Wc = Wo + (size_t)(q * 128) * 512 + d;
    float acc = 0.f;
    #pragma unroll 4
    for (int e = 0; e < 128; ++e) acc = fmaf(x[e], Wc[(size_t)e * 512], acc);
    red[t] = acc; __syncthreads();
    if (t < 64)
        ((float*)frow4)[t] = red[t] + red[t+64] + red[t+128] + red[t+192]
                           + bo[dt * 64 + t];
    __syncthreads();

    // write 128 rows x 64 cols; thread -> (row r0 + k*16, float4-col t&15)
    int col4 = t & 15, r0 = t >> 4;
    float4 val = frow4[col4];
    float4* o4 = (float4*)out + ((size_t)b * 2048 + is * 128) * 128 + dt * 16;
    #pragma unroll
    for (int rr = r0; rr < 128; rr += 16)
        o4[(size_t)rr * 128 + col4] = val;
}

extern "C" void kernel_launch(void* const* d_in, const int* in_sizes, int n_in,
                              void* d_out, int out_size, void* d_ws, size_t ws_size,
                              hipStream_t stream) {
    // setup_inputs order: query, key, value, Wq, bq, Wk, bk, Wv, bv, Wo, bo
    const float* key   = (const float*)d_in[1];
    const float* value = (const float*)d_in[2];
    const float* Wk    = (const float*)d_in[5];
    const float* bk    = (const float*)d_in[6];
    const float* Wv    = (const float*)d_in[7];
    const float* bv    = (const float*)d_in[8];
    const float* Wo    = (const float*)d_in[9];
    const float* bo    = (const float*)d_in[10];
    float* out = (float*)d_out;
    float* ws  = (float*)d_ws;

    // workspace layout (floats), ~1.1 MB
    float* w        = ws;                 // 16384
    float* partial  = ws + 16384;         // 8*64*512 = 262144
    float* partialw = ws + 278528;        // 512
    float* ctx      = ws + 279040;        // 4096

    k_scores<<<512, 256, 0, stream>>>(key, Wk, bk, w);
    k_wsum  <<<dim3(64, 8), 256, 0, stream>>>(value, w, partial, partialw);
    k_ctx   <<<dim3(8, 8), 256, 0, stream>>>(partial, partialw, Wv, bv, ctx);
    k_out   <<<dim3(8, 8, 16), 256, 0, stream>>>(ctx, Wo, bo, out);
}

// Round 4
// 186.904 us; speedup vs baseline: 1.1422x; 1.0104x over previous
//
#include <hip/hip_runtime.h>
#include <math.h>

#define DEV __device__ __forceinline__

struct C2 { float x, y; };
DEV C2 cmul(C2 a, C2 b){ return {a.x*b.x - a.y*b.y, a.x*b.y + a.y*b.x}; }
DEV C2 cadd(C2 a, C2 b){ return {a.x+b.x, a.y+b.y}; }
DEV C2 cscale(C2 a, float s){ return {a.x*s, a.y*s}; }
DEV C2 cnegi(C2 a){ return {a.y, -a.x}; } // multiply by -i

// ---------------------------------------------------------------------------
// K1 (fused): per block (c,b) -> rows r = b*2048 + c*32 + j, j in [0,32).
// Phase A: wave wv computes w[j]=exp(score) for rows j = wv*8..wv*8+7
//          (k_states = key@Wk+bk via in-register Wk slice + butterfly
//          reduce; analytic 2-qubit-pair score). w -> LDS.
// Phase B: unnormalized weighted sum of the 32 value rows (float4 cols,
//          two 16-row groups LDS-combined) + per-chunk w-sum.
// Kills the separate k_wsum dispatch and the w global round-trip.
// ---------------------------------------------------------------------------
__global__ __launch_bounds__(256) void k_score_wsum(const float* __restrict__ key,
                                                    const float* __restrict__ Wk,
                                                    const float* __restrict__ bk,
                                                    const float* __restrict__ value,
                                                    float* __restrict__ partial,
                                                    float* __restrict__ partialw)
{
    const int c = blockIdx.x;        // 0..63
    const int b = blockIdx.y;        // 0..7
    const int t = threadIdx.x;
    const int lane = t & 63;
    const int wv   = t >> 6;         // wave 0..3
    const int base = b * 2048 + c * 32;

    __shared__ float wlds[32];
    __shared__ float4 tmp[128];

    // per-lane Wk slice: rows 4l..4l+3 and 256+4l..256+4l+3, all 16 cols
    float4 wk[8][4];
    #pragma unroll
    for (int jj = 0; jj < 4; ++jj) {
        const float4* w0 = (const float4*)(Wk + (4 * lane + jj) * 16);
        const float4* w1 = (const float4*)(Wk + (256 + 4 * lane + jj) * 16);
        #pragma unroll
        for (int q = 0; q < 4; ++q) { wk[jj][q] = w0[q]; wk[4 + jj][q] = w1[q]; }
    }
    const float bkr = bk[lane & 15];
    const float c0 = 0.30901699437494745f;   // cos(pi*0.8/2)
    const float s0 = 0.9510565162951535f;    // sin(pi*0.8/2)

    // ---- Phase A: scores for this block's 32 rows ----
    #pragma unroll 2
    for (int i = 0; i < 8; ++i) {
        const int j = wv * 8 + i;
        const float4* kp = (const float4*)(key + (size_t)(base + j) * 512);
        float4 k0 = kp[lane];       // e = 4l..4l+3
        float4 k1 = kp[64 + lane];  // e = 256+4l..+3
        float el[8] = {k0.x, k0.y, k0.z, k0.w, k1.x, k1.y, k1.z, k1.w};
        float acc[16];
        #pragma unroll
        for (int k = 0; k < 16; ++k) acc[k] = 0.f;
        #pragma unroll
        for (int jr = 0; jr < 8; ++jr) {
            #pragma unroll
            for (int q = 0; q < 4; ++q) {
                acc[4*q+0] = fmaf(el[jr], wk[jr][q].x, acc[4*q+0]);
                acc[4*q+1] = fmaf(el[jr], wk[jr][q].y, acc[4*q+1]);
                acc[4*q+2] = fmaf(el[jr], wk[jr][q].z, acc[4*q+2]);
                acc[4*q+3] = fmaf(el[jr], wk[jr][q].w, acc[4*q+3]);
            }
        }
        // butterfly: after 4 stages acc[0] holds output (lane&15) for this
        // 16-lane group's e's; then fold the 4 groups.
        #pragma unroll
        for (int s = 0; s < 4; ++s) {
            const int m = 1 << s;
            const int bbit = (lane >> s) & 1;
            #pragma unroll
            for (int jj = 0; jj < (16 >> (s + 1)); ++jj) {
                float send = bbit ? acc[2*jj] : acc[2*jj+1];
                float keep = bbit ? acc[2*jj+1] : acc[2*jj];
                float got  = __shfl_xor(send, m);
                acc[jj] = keep + got;
            }
        }
        float ks = acc[0];
        ks += __shfl_xor(ks, 16);
        ks += __shfl_xor(ks, 32);
        ks += bkr;                  // lane l holds k_states[row][l & 15]

        // quantum score: lane handles pair pp = l&3
        int pp = lane & 3;
        float ax = __shfl(ks, 4*pp+0);
        float az = __shfl(ks, 4*pp+1);
        float bx = __shfl(ks, 4*pp+2);
        float bz = __shfl(ks, 4*pp+3);
        float cxa = 1.f, sxa = 0.f; if (ax > 0.f){ sxa = __sinf(0.5f*ax); cxa = __cosf(0.5f*ax); }
        float cpa = 1.f, spa = 0.f; if (az > 0.f){ spa = __sinf(0.5f*az); cpa = __cosf(0.5f*az); }
        float cxb = 1.f, sxb = 0.f; if (bx > 0.f){ sxb = __sinf(0.5f*bx); cxb = __cosf(0.5f*bx); }
        float cpb = 1.f, spb = 0.f; if (bz > 0.f){ spb = __sinf(0.5f*bz); cpb = __cosf(0.5f*bz); }
        C2 A00{cpa*cxa, -spa*cxa}, A01{-spa*sxa, -cpa*sxa};
        C2 A10{spa*sxa, -cpa*sxa}, A11{ cpa*cxa,  spa*cxa};
        C2 B00{cpb*cxb, -spb*cxb}, B01{-spb*sxb, -cpb*sxb};
        C2 B10{spb*sxb, -cpb*sxb}, B11{ cpb*cxb,  spb*cxb};
        C2 u = cadd(cmul(B00, cadd(A00, cscale(A01, c0))),
                    cscale(cnegi(cmul(A01, B01)), s0));
        C2 v = cadd(cmul(B10, cadd(A10, cscale(A11, c0))),
                    cscale(cnegi(cmul(A11, B11)), s0));
        float ps = u.x*u.x + u.y*u.y + v.x*v.x + v.y*v.y;
        ps += __shfl_xor(ps, 1);
        ps += __shfl_xor(ps, 2);    // sum over the 4 pairs
        if (lane == 0) wlds[j] = __expf(ps * 0.125f);  // *0.5 (norm) *0.25 (mean)
    }
    __syncthreads();

    // ---- Phase B: weighted value sum + chunk w-sum ----
    const int col4 = t & 127, rg = t >> 7;
    const float4* vbase = (const float4*)value
        + ((size_t)base + rg * 16) * 128 + col4;
    float4 acc = {0.f, 0.f, 0.f, 0.f};
    #pragma unroll 4
    for (int j = 0; j < 16; ++j) {
        float wj = wlds[rg * 16 + j];         // uniform per half-block
        float4 v = vbase[(size_t)j * 128];
        acc.x = fmaf(wj, v.x, acc.x); acc.y = fmaf(wj, v.y, acc.y);
        acc.z = fmaf(wj, v.z, acc.z); acc.w = fmaf(wj, v.w, acc.w);
    }
    if (rg) tmp[col4] = acc;
    __syncthreads();
    if (!rg) {
        float4 o = tmp[col4];
        acc.x += o.x; acc.y += o.y; acc.z += o.z; acc.w += o.w;
        ((float4*)partial)[((size_t)b*64 + c) * 128 + col4] = acc;
    }
    if (t < 32) {
        float s = wlds[t];
        s += __shfl_xor(s, 1);  s += __shfl_xor(s, 2);
        s += __shfl_xor(s, 4);  s += __shfl_xor(s, 8);
        s += __shfl_xor(s, 16);
        if (t == 0) partialw[b * 64 + c] = s;
    }
}

// ---------------------------------------------------------------------------
// K2: per block (dt, b): invS = 1/sum(partialw[b,:]); vbar = invS * reduce
// partial over chunks (into LDS); ctx[b, dt*64..+64] = vbar @ Wv + bv.
// ---------------------------------------------------------------------------
__global__ __launch_bounds__(256) void k_ctx(const float* __restrict__ partial,
                                             const float* __restrict__ partialw,
                                             const float* __restrict__ Wv,
                                             const float* __restrict__ bv,
                                             float* __restrict__ ctx)
{
    int dt = blockIdx.x, b = blockIdx.y, t = threadIdx.x;
    __shared__ float vb[512];
    __shared__ float invS;
    __shared__ float red[256];

    if (t < 64) {
        float s = partialw[b * 64 + t];
        s += __shfl_xor(s, 1);  s += __shfl_xor(s, 2);
        s += __shfl_xor(s, 4);  s += __shfl_xor(s, 8);
        s += __shfl_xor(s, 16); s += __shfl_xor(s, 32);
        if (t == 0) invS = 1.f / s;
    }
    float a0 = 0.f, a1 = 0.f;
    const float* pp = partial + (size_t)b * 64 * 512;
    #pragma unroll 4
    for (int c = 0; c < 64; ++c) {
        a0 += pp[c * 512 + t];
        a1 += pp[c * 512 + 256 + t];
    }
    __syncthreads();                 // invS visible
    vb[t] = a0 * invS; vb[t + 256] = a1 * invS;
    __syncthreads();                 // vb visible

    int dl = t & 63, q = t >> 6;
    int d = dt * 64 + dl;
    const float* x  = vb + q * 128;
    const float* Wc = Wv + (size_t)(q * 128) * 512 + d;
    float acc = 0.f;
    #pragma unroll 4
    for (int e = 0; e < 128; ++e) acc = fmaf(x[e], Wc[(size_t)e * 512], acc);
    red[t] = acc; __syncthreads();
    if (t < 64)
        ctx[b * 512 + dt * 64 + t] = red[t] + red[t+64] + red[t+128] + red[t+192]
                                   + bv[dt * 64 + t];
}

// ---------------------------------------------------------------------------
// K3: per block (dt, b, is): frow_tile = ctx[b,:] @ Wo[:, dt*64..+64] + bo,
// broadcast-written to out[b, is*128..+128, dt*64..+64].
// ---------------------------------------------------------------------------
__global__ __launch_bounds__(256) void k_out(const float* __restrict__ ctx,
                                             const float* __restrict__ Wo,
                                             const float* __restrict__ bo,
                                             float* __restrict__ out)
{
    int dt = blockIdx.x, b = blockIdx.y, is = blockIdx.z, t = threadIdx.x;
    __shared__ float xs[512];
    __shared__ float red[256];
    __shared__ float4 frow4[16];

    xs[t]       = ctx[b * 512 + t];
    xs[t + 256] = ctx[b * 512 + 256 + t];
    __syncthreads();

    int dl = t & 63, q = t >> 6;
    int d = dt * 64 + dl;
    const float* x  = xs + q * 128;
    const float* Wc = Wo + (size_t)(q * 128) * 512 + d;
    float acc = 0.f;
    #pragma unroll 4
    for (int e = 0; e < 128; ++e) acc = fmaf(x[e], Wc[(size_t)e * 512], acc);
    red[t] = acc; __syncthreads();
    if (t < 64)
        ((float*)frow4)[t] = red[t] + red[t+64] + red[t+128] + red[t+192]
                           + bo[dt * 64 + t];
    __syncthreads();

    // write 128 rows x 64 cols; thread -> (rows r0+16k, float4-col t&15)
    int col4 = t & 15, r0 = t >> 4;
    float4 val = frow4[col4];
    float4* o4 = (float4*)out + ((size_t)b * 2048 + is * 128) * 128 + dt * 16;
    #pragma unroll
    for (int rr = r0; rr < 128; rr += 16)
        o4[(size_t)rr * 128 + col4] = val;
}

extern "C" void kernel_launch(void* const* d_in, const int* in_sizes, int n_in,
                              void* d_out, int out_size, void* d_ws, size_t ws_size,
                              hipStream_t stream) {
    // setup_inputs order: query, key, value, Wq, bq, Wk, bk, Wv, bv, Wo, bo
    const float* key   = (const float*)d_in[1];
    const float* value = (const float*)d_in[2];
    const float* Wk    = (const float*)d_in[5];
    const float* bk    = (const float*)d_in[6];
    const float* Wv    = (const float*)d_in[7];
    const float* bv    = (const float*)d_in[8];
    const float* Wo    = (const float*)d_in[9];
    const float* bo    = (const float*)d_in[10];
    float* out = (float*)d_out;
    float* ws  = (float*)d_ws;

    // workspace layout (floats), ~1.1 MB
    float* partial  = ws;                 // 8*64*512 = 262144
    float* partialw = ws + 262144;        // 512
    float* ctx      = ws + 262656;        // 4096

    k_score_wsum<<<dim3(64, 8), 256, 0, stream>>>(key, Wk, bk, value,
                                                  partial, partialw);
    k_ctx       <<<dim3(8, 8), 256, 0, stream>>>(partial, partialw, Wv, bv, ctx);
    k_out       <<<dim3(8, 8, 16), 256, 0, stream>>>(ctx, Wo, bo, out);
}